// Round 1
// baseline (1098.049 us; speedup 1.0000x reference)
//
#include <hip/hip_runtime.h>
#include <math.h>

#define B_   2
#define S_   4
#define C_   64
#define HW_  65536
#define CI_  194
#define CO_  24
#define ENC_ 96
#define HID_ 64

__device__ __forceinline__ float gelu_f(float x){
  return 0.5f*x*(1.0f+erff(x*0.70710678118654752f));
}

// ---------------- prep: E1 = W_Sz + W_delta, E2 = W_Tz - W_delta, c0 = pos constants
__global__ void kPrep(const float* __restrict__ encw, float* __restrict__ E1,
                      float* __restrict__ E2, float* __restrict__ c0){
  int t = blockIdx.x*blockDim.x + threadIdx.x;
  int tot = S_*CO_*C_;
  for (int idx=t; idx<tot; idx += gridDim.x*blockDim.x){
    int c  = idx & (C_-1);
    int so = idx >> 6;            // s*CO + o
    const float* row = encw + so*CI_;
    E1[idx] = row[c]      + row[2*C_+c];
    E2[idx] = row[C_+c]   - row[2*C_+c];
  }
  if (t < S_*CO_){
    int s = t / CO_;
    float idxv = (float)s / 3.0f;
    float ang  = 6.283185307179586f * idxv;
    const float* row = encw + t*CI_;
    c0[t] = row[3*C_]*sinf(ang) + row[3*C_+1]*cosf(ang);
  }
}

// ---------------- kernel A: adapter matvecs, proxy/heur, enc
__global__ __launch_bounds__(256, 2) void kAdapterEnc(
    const float* __restrict__ Sf, const float* __restrict__ Tf,
    const float* __restrict__ adW, const float* __restrict__ adB,
    const float* __restrict__ mu, const float* __restrict__ sg,
    const float* __restrict__ eproxy,
    const float* __restrict__ E1, const float* __restrict__ E2,
    const float* __restrict__ c0,
    float* __restrict__ enc, float* __restrict__ heur)
{
  const int hw = blockIdx.x*256 + threadIdx.x;
  const int b  = blockIdx.y;

  float s_in[C_];
#pragma unroll
  for (int i=0;i<C_;i++) s_in[i] = Sf[(b*C_+i)*HW_ + hw];

  for (int s=0;s<S_;s++){
    float t_in[C_];
#pragma unroll
    for (int i=0;i<C_;i++) t_in[i] = Tf[((b*S_+s)*C_+i)*HW_ + hw];

    float eacc[CO_];
#pragma unroll
    for (int e=0;e<CO_;e++) eacc[e] = c0[s*CO_+e];
    float pacc = 0.0f;

    for (int oc=0; oc<C_; oc+=8){
      float ta[8], sr[8];
#pragma unroll
      for (int oo=0;oo<8;oo++){ float bb = adB[s*C_+oc+oo]; ta[oo]=bb; sr[oo]=bb; }
#pragma unroll
      for (int i=0;i<C_;i++){
#pragma unroll
        for (int oo=0;oo<8;oo++){
          float w = adW[(s*C_+oc+oo)*C_ + i];
          ta[oo] = fmaf(w, t_in[i], ta[oo]);
          sr[oo] = fmaf(w, s_in[i], sr[oo]);
        }
      }
      float tz[8], sz[8];
#pragma unroll
      for (int oo=0;oo<8;oo++){
        float m   = mu[s*C_+oc+oo];
        float sig = fmaxf(sg[s*C_+oc+oo], 1e-3f);
        float inv = 1.0f/sig;
        tz[oo] = (ta[oo]-m)*inv;
        sz[oo] = (sr[oo]-m)*inv;
        float d = sz[oo]-tz[oo];
        pacc = fmaf(d,d,pacc);
      }
#pragma unroll
      for (int e=0;e<CO_;e++){
        float acc = eacc[e];
#pragma unroll
        for (int oo=0;oo<8;oo++){
          acc = fmaf(E1[(s*CO_+e)*C_+oc+oo], sz[oo], acc);
          acc = fmaf(E2[(s*CO_+e)*C_+oc+oo], tz[oo], acc);
        }
        eacc[e]=acc;
      }
    }
    float proxy = pacc*(1.0f/(float)C_);
    float adv   = proxy - eproxy[s];
    float band  = (proxy>=0.05f && proxy<=0.2f)?1.0f:0.0f;
    heur[(b*S_+s)*HW_+hw] = adv + 0.5f*band;
#pragma unroll
    for (int e=0;e<CO_;e++) enc[((b*S_+s)*CO_+e)*HW_+hw] = eacc[e];
  }
}

// ---------------- segmented group-norm stats (one block per (group, b, segment))
__global__ __launch_bounds__(256) void kStatsPart(const float* __restrict__ x, int npg, int nct,
  float* __restrict__ psum, float* __restrict__ psq)
{
  const int g=blockIdx.x, b=blockIdx.y, seg=blockIdx.z;
  float sum=0.f, sq=0.f;
  for (int j=0;j<npg;j++){
    const float4* row=(const float4*)(x + (size_t)(b*nct+g*npg+j)*HW_) + seg*(HW_/16);
    for (int i=threadIdx.x;i<HW_/16;i+=256){
      float4 v=row[i];
      sum += (v.x+v.y)+(v.z+v.w);
      sq = fmaf(v.x,v.x,sq); sq=fmaf(v.y,v.y,sq); sq=fmaf(v.z,v.z,sq); sq=fmaf(v.w,v.w,sq);
    }
  }
#pragma unroll
  for (int off=32;off>=1;off>>=1){ sum+=__shfl_xor(sum,off); sq+=__shfl_xor(sq,off); }
  __shared__ float ss[4], qq[4];
  int wid=threadIdx.x>>6, lane=threadIdx.x&63;
  if(lane==0){ ss[wid]=sum; qq[wid]=sq; }
  __syncthreads();
  if(threadIdx.x==0){
    psum[(b*32+g)*4+seg]=ss[0]+ss[1]+ss[2]+ss[3];
    psq [(b*32+g)*4+seg]=qq[0]+qq[1]+qq[2]+qq[3];
  }
}

// ---------------- finalize GN coefficients: y = a*x + c per (b, channel)
__global__ void kFinalize(const float* __restrict__ psum, const float* __restrict__ psq,
  const float* __restrict__ gamma, const float* __restrict__ beta,
  int npg, int nct, float* __restrict__ cA, float* __restrict__ cB)
{
  int t=threadIdx.x;
  if (t < B_*32){
    int b=t>>5, g=t&31;
    float Ssum=0.f,Q=0.f;
    for(int k=0;k<4;k++){ Ssum+=psum[t*4+k]; Q+=psq[t*4+k]; }
    float n=(float)npg*(float)HW_;
    float mean=Ssum/n;
    float var=Q/n-mean*mean;
    float inv=1.0f/sqrtf(var+1e-5f);
    for(int j=0;j<npg;j++){
      int c=g*npg+j;
      float a=gamma[c]*inv;
      cA[b*nct+c]=a;
      cB[b*nct+c]=beta[c]-mean*a;
    }
  }
}

// ---------------- kernel C: gelu(GN1(enc)) -> mix1 -> h1
__global__ __launch_bounds__(256, 2) void kMix1(
  const float* __restrict__ enc, const float* __restrict__ cA1, const float* __restrict__ cB1,
  const float* __restrict__ m1w, float* __restrict__ h1)
{
  const int hw=blockIdx.x*256+threadIdx.x;
  const int b=blockIdx.y;
  float g[ENC_];
#pragma unroll
  for (int c=0;c<ENC_;c++){
    float v=enc[(b*ENC_+c)*HW_+hw];
    v=fmaf(v,cA1[b*ENC_+c],cB1[b*ENC_+c]);
    g[c]=gelu_f(v);
  }
  for (int o=0;o<HID_;o+=16){
    float acc[16];
#pragma unroll
    for(int k=0;k<16;k++) acc[k]=0.f;
#pragma unroll
    for (int c=0;c<ENC_;c++){
#pragma unroll
      for (int k=0;k<16;k++) acc[k]=fmaf(m1w[(o+k)*ENC_+c], g[c], acc[k]);
    }
#pragma unroll
    for (int k=0;k<16;k++) h1[(b*HID_+o+k)*HW_+hw]=acc[k];
  }
}

// ---------------- kernel E: gelu(GN2(h1)) -> mix2 -> softmax gates -> fused (T_adapt recomputed)
__global__ __launch_bounds__(256, 2) void kFinal(
  const float* __restrict__ Tf, const float* __restrict__ adW, const float* __restrict__ adB,
  const float* __restrict__ h1, const float* __restrict__ heur,
  const float* __restrict__ cA2, const float* __restrict__ cB2,
  const float* __restrict__ m2w, const float* __restrict__ m2b,
  float* __restrict__ out)
{
  const int hw = blockIdx.x*256+threadIdx.x;
  const int b  = blockIdx.y;
  float g[HID_];
#pragma unroll
  for (int c=0;c<HID_;c++){
    float v = h1[(b*HID_+c)*HW_+hw];
    v = fmaf(v, cA2[b*HID_+c], cB2[b*HID_+c]);
    g[c] = gelu_f(v);
  }
  float g0,g1,g2,g3;
  {
    float logits[S_];
    float mx=-1e30f;
#pragma unroll
    for (int s=0;s<S_;s++){
      float acc = m2b[s];
#pragma unroll
      for (int c=0;c<HID_;c++) acc = fmaf(m2w[s*HID_+c], g[c], acc);
      float hv = heur[(b*S_+s)*HW_+hw];
      float l  = (0.5f*hv + 0.5f*acc)/0.7f;
      logits[s]=l; mx=fmaxf(mx,l);
    }
    float e0=expf(logits[0]-mx), e1=expf(logits[1]-mx),
          e2=expf(logits[2]-mx), e3=expf(logits[3]-mx);
    float dinv = 1.0f/(e0+e1+e2+e3);
    g0=e0*dinv; g1=e1*dinv; g2=e2*dinv; g3=e3*dinv;
  }

  float oacc[C_];
#pragma unroll
  for (int c=0;c<C_;c++) oacc[c]=0.f;

  for (int s=0;s<S_;s++){
    float gt = (s==0)?g0:((s==1)?g1:((s==2)?g2:g3));
    float t_in[C_];
#pragma unroll
    for (int i=0;i<C_;i++) t_in[i]=Tf[((b*S_+s)*C_+i)*HW_+hw];
#pragma unroll
    for (int oc=0;oc<C_;oc+=8){
      float ta[8];
#pragma unroll
      for (int oo=0;oo<8;oo++) ta[oo]=adB[s*C_+oc+oo];
#pragma unroll
      for (int i=0;i<C_;i++){
#pragma unroll
        for (int oo=0;oo<8;oo++)
          ta[oo]=fmaf(adW[(s*C_+oc+oo)*C_+i], t_in[i], ta[oo]);
      }
#pragma unroll
      for (int oo=0;oo<8;oo++) oacc[oc+oo]=fmaf(gt, ta[oo], oacc[oc+oo]);
    }
  }
#pragma unroll
  for (int c=0;c<C_;c++) out[(b*C_+c)*HW_+hw]=oacc[c];
}

extern "C" void kernel_launch(void* const* d_in, const int* in_sizes, int n_in,
                              void* d_out, int out_size, void* d_ws, size_t ws_size,
                              hipStream_t stream) {
  (void)in_sizes; (void)n_in; (void)out_size; (void)ws_size;
  const float* Sf    = (const float*)d_in[0];
  const float* Tf    = (const float*)d_in[1];
  const float* adW   = (const float*)d_in[2];
  const float* adB   = (const float*)d_in[3];
  const float* mu    = (const float*)d_in[4];
  const float* sg    = (const float*)d_in[5];
  const float* eprox = (const float*)d_in[6];
  const float* encw  = (const float*)d_in[7];
  const float* gn1g  = (const float*)d_in[8];
  const float* gn1b  = (const float*)d_in[9];
  const float* m1w   = (const float*)d_in[10];
  const float* gn2g  = (const float*)d_in[11];
  const float* gn2b  = (const float*)d_in[12];
  const float* m2w   = (const float*)d_in[13];
  const float* m2b   = (const float*)d_in[14];
  float* out = (float*)d_out;

  float* ws = (float*)d_ws;
  size_t off = 0;
  float* enc  = ws+off; off += (size_t)B_*ENC_*HW_;   // 12,582,912
  float* h1   = ws+off; off += (size_t)B_*HID_*HW_;   //  8,388,608
  float* heur = ws+off; off += (size_t)B_*S_*HW_;     //    524,288
  float* E1   = ws+off; off += S_*CO_*C_;             //      6,144
  float* E2   = ws+off; off += S_*CO_*C_;
  float* c0   = ws+off; off += S_*CO_;
  float* ps1  = ws+off; off += B_*32*4;
  float* pq1  = ws+off; off += B_*32*4;
  float* ps2  = ws+off; off += B_*32*4;
  float* pq2  = ws+off; off += B_*32*4;
  float* cA1  = ws+off; off += B_*ENC_;
  float* cB1  = ws+off; off += B_*ENC_;
  float* cA2  = ws+off; off += B_*HID_;
  float* cB2  = ws+off; off += B_*HID_;

  kPrep<<<dim3(24), 256, 0, stream>>>(encw, E1, E2, c0);
  kAdapterEnc<<<dim3(HW_/256, B_), 256, 0, stream>>>(Sf, Tf, adW, adB, mu, sg, eprox,
                                                     E1, E2, c0, enc, heur);
  kStatsPart<<<dim3(32, B_, 4), 256, 0, stream>>>(enc, 3, ENC_, ps1, pq1);
  kFinalize<<<1, 64, 0, stream>>>(ps1, pq1, gn1g, gn1b, 3, ENC_, cA1, cB1);
  kMix1<<<dim3(HW_/256, B_), 256, 0, stream>>>(enc, cA1, cB1, m1w, h1);
  kStatsPart<<<dim3(32, B_, 4), 256, 0, stream>>>(h1, 2, HID_, ps2, pq2);
  kFinalize<<<1, 64, 0, stream>>>(ps2, pq2, gn2g, gn2b, 2, HID_, cA2, cB2);
  kFinal<<<dim3(HW_/256, B_), 256, 0, stream>>>(Tf, adW, adB, h1, heur,
                                                cA2, cB2, m2w, m2b, out);
}

// Round 4
// 1068.676 us; speedup vs baseline: 1.0275x; 1.0275x over previous
//
#include <hip/hip_runtime.h>
#include <math.h>

#define B_   2
#define S_   4
#define C_   64
#define HW_  65536
#define CI_  194
#define CO_  24
#define ENC_ 96
#define HID_ 64
#define NSEG 8

__device__ __forceinline__ float gelu_f(float x){
  return 0.5f*x*(1.0f+erff(x*0.70710678118654752f));
}

// ---------------- prep: E1 = W_Sz + W_delta, E2 = W_Tz - W_delta, c0 = pos constants
__global__ void kPrep(const float* __restrict__ encw, float* __restrict__ E1,
                      float* __restrict__ E2, float* __restrict__ c0){
  int t = blockIdx.x*blockDim.x + threadIdx.x;
  int tot = S_*CO_*C_;
  for (int idx=t; idx<tot; idx += gridDim.x*blockDim.x){
    int c  = idx & (C_-1);
    int so = idx >> 6;            // s*CO + o
    const float* row = encw + so*CI_;
    E1[idx] = row[c]      + row[2*C_+c];
    E2[idx] = row[C_+c]   - row[2*C_+c];
  }
  if (t < S_*CO_){
    int s = t / CO_;
    float idxv = (float)s / 3.0f;
    float ang  = 6.283185307179586f * idxv;
    const float* row = encw + t*CI_;
    c0[t] = row[3*C_]*sinf(ang) + row[3*C_+1]*cosf(ang);
  }
}

// ---------------- kernel A: adapter matvecs, proxy/heur, enc — one (b,s) per block-z
__global__ __launch_bounds__(256, 4) void kAdapterEnc(
    const float* __restrict__ Sf, const float* __restrict__ Tf,
    const float* __restrict__ adW, const float* __restrict__ adB,
    const float* __restrict__ mu, const float* __restrict__ sg,
    const float* __restrict__ eproxy,
    const float* __restrict__ E1, const float* __restrict__ E2,
    const float* __restrict__ c0,
    float* __restrict__ enc, float* __restrict__ heur)
{
  const int hw = blockIdx.x*256 + threadIdx.x;
  const int b  = blockIdx.y;
  const int s  = blockIdx.z;

  __shared__ float w_sh[C_][C_];       // [oc][i]  16 KB
  __shared__ float e_sh[C_][2*CO_];    // [oc][e]=E1, [oc][CO_+e]=E2   12 KB
  __shared__ float bias_sh[C_], mu_sh[C_], inv_sh[C_], c0_sh[CO_];

  for (int idx=threadIdx.x; idx<C_*C_; idx+=256){
    int oc=idx>>6, i=idx&63;
    w_sh[oc][i] = adW[(s*C_+oc)*C_+i];
  }
  for (int idx=threadIdx.x; idx<C_*CO_; idx+=256){
    int oc=idx/CO_, e=idx-oc*CO_;
    e_sh[oc][e]     = E1[(s*CO_+e)*C_+oc];
    e_sh[oc][CO_+e] = E2[(s*CO_+e)*C_+oc];
  }
  if (threadIdx.x<C_){
    bias_sh[threadIdx.x]=adB[s*C_+threadIdx.x];
    mu_sh[threadIdx.x]  =mu [s*C_+threadIdx.x];
    inv_sh[threadIdx.x] =1.0f/fmaxf(sg[s*C_+threadIdx.x],1e-3f);
  }
  if (threadIdx.x<CO_) c0_sh[threadIdx.x]=c0[s*CO_+threadIdx.x];
  __syncthreads();

  const float* tbase = Tf + ((size_t)(b*S_+s)*C_)*HW_ + hw;
  const float* sbase = Sf + ((size_t)b*C_)*HW_ + hw;

  float eacc[CO_];
#pragma unroll
  for (int e=0;e<CO_;e++) eacc[e]=c0_sh[e];
  float pacc=0.f;

  for (int oc0=0; oc0<C_; oc0+=16){
    float ta[16], sr[16];
#pragma unroll
    for (int k=0;k<16;k++){ ta[k]=bias_sh[oc0+k]; sr[k]=ta[k]; }

    for (int i0=0;i0<C_;i0+=8){
      float ti[8], si[8];
#pragma unroll
      for (int ii=0;ii<8;ii++){
        ti[ii]=tbase[(size_t)(i0+ii)*HW_];
        si[ii]=sbase[(size_t)(i0+ii)*HW_];
      }
#pragma unroll
      for (int k=0;k<16;k++){
        float4 w0=*(const float4*)&w_sh[oc0+k][i0];
        float4 w1=*(const float4*)&w_sh[oc0+k][i0+4];
        ta[k]=fmaf(w0.x,ti[0],ta[k]); sr[k]=fmaf(w0.x,si[0],sr[k]);
        ta[k]=fmaf(w0.y,ti[1],ta[k]); sr[k]=fmaf(w0.y,si[1],sr[k]);
        ta[k]=fmaf(w0.z,ti[2],ta[k]); sr[k]=fmaf(w0.z,si[2],sr[k]);
        ta[k]=fmaf(w0.w,ti[3],ta[k]); sr[k]=fmaf(w0.w,si[3],sr[k]);
        ta[k]=fmaf(w1.x,ti[4],ta[k]); sr[k]=fmaf(w1.x,si[4],sr[k]);
        ta[k]=fmaf(w1.y,ti[5],ta[k]); sr[k]=fmaf(w1.y,si[5],sr[k]);
        ta[k]=fmaf(w1.z,ti[6],ta[k]); sr[k]=fmaf(w1.z,si[6],sr[k]);
        ta[k]=fmaf(w1.w,ti[7],ta[k]); sr[k]=fmaf(w1.w,si[7],sr[k]);
      }
    }
    // normalize + proxy + enc accumulate for this oc chunk
#pragma unroll
    for (int k=0;k<16;k++){
      int oc=oc0+k;
      float m=mu_sh[oc], inv=inv_sh[oc];
      float tz=(ta[k]-m)*inv;
      float sz=(sr[k]-m)*inv;
      float d=sz-tz; pacc=fmaf(d,d,pacc);
#pragma unroll
      for (int e0=0;e0<CO_;e0+=4){
        float4 E1v=*(const float4*)&e_sh[oc][e0];
        float4 E2v=*(const float4*)&e_sh[oc][CO_+e0];
        eacc[e0+0]=fmaf(E1v.x,sz,fmaf(E2v.x,tz,eacc[e0+0]));
        eacc[e0+1]=fmaf(E1v.y,sz,fmaf(E2v.y,tz,eacc[e0+1]));
        eacc[e0+2]=fmaf(E1v.z,sz,fmaf(E2v.z,tz,eacc[e0+2]));
        eacc[e0+3]=fmaf(E1v.w,sz,fmaf(E2v.w,tz,eacc[e0+3]));
      }
    }
  }

  float proxy = pacc*(1.0f/(float)C_);
  float adv   = proxy - eproxy[s];
  float band  = (proxy>=0.05f && proxy<=0.2f)?1.0f:0.0f;
  heur[((size_t)(b*S_+s))*HW_+hw] = adv + 0.5f*band;
#pragma unroll
  for (int e=0;e<CO_;e++) enc[((size_t)((b*S_+s)*CO_+e))*HW_+hw] = eacc[e];
}

// ---------------- segmented group-norm stats
__global__ __launch_bounds__(256) void kStatsPart(const float* __restrict__ x, int npg, int nct,
  float* __restrict__ psum, float* __restrict__ psq)
{
  const int g=blockIdx.x, b=blockIdx.y, seg=blockIdx.z;
  const int F4_PER_SEG = HW_/4/NSEG;   // 2048
  float sum=0.f, sq=0.f;
  for (int j=0;j<npg;j++){
    const float4* row=(const float4*)(x + (size_t)(b*nct+g*npg+j)*HW_) + seg*F4_PER_SEG;
    for (int i=threadIdx.x;i<F4_PER_SEG;i+=256){
      float4 v=row[i];
      sum += (v.x+v.y)+(v.z+v.w);
      sq = fmaf(v.x,v.x,sq); sq=fmaf(v.y,v.y,sq); sq=fmaf(v.z,v.z,sq); sq=fmaf(v.w,v.w,sq);
    }
  }
#pragma unroll
  for (int off=32;off>=1;off>>=1){ sum+=__shfl_xor(sum,off); sq+=__shfl_xor(sq,off); }
  __shared__ float ss[4], qq[4];
  int wid=threadIdx.x>>6, lane=threadIdx.x&63;
  if(lane==0){ ss[wid]=sum; qq[wid]=sq; }
  __syncthreads();
  if(threadIdx.x==0){
    psum[(b*32+g)*NSEG+seg]=ss[0]+ss[1]+ss[2]+ss[3];
    psq [(b*32+g)*NSEG+seg]=qq[0]+qq[1]+qq[2]+qq[3];
  }
}

// ---------------- finalize GN coefficients
__global__ void kFinalize(const float* __restrict__ psum, const float* __restrict__ psq,
  const float* __restrict__ gamma, const float* __restrict__ beta,
  int npg, int nct, float* __restrict__ cA, float* __restrict__ cB)
{
  int t=threadIdx.x;
  if (t < B_*32){
    int b=t>>5, g=t&31;
    float Ssum=0.f,Q=0.f;
    for(int k=0;k<NSEG;k++){ Ssum+=psum[t*NSEG+k]; Q+=psq[t*NSEG+k]; }
    float n=(float)npg*(float)HW_;
    float mean=Ssum/n;
    float var=Q/n-mean*mean;
    float inv=1.0f/sqrtf(var+1e-5f);
    for(int j=0;j<npg;j++){
      int c=g*npg+j;
      float a=gamma[c]*inv;
      cA[b*nct+c]=a;
      cB[b*nct+c]=beta[c]-mean*a;
    }
  }
}

// ---------------- kernel C: gelu(GN1(enc)) -> mix1 (half of outputs per block-z)
__global__ __launch_bounds__(256, 4) void kMix1(
  const float* __restrict__ enc, const float* __restrict__ cA1, const float* __restrict__ cB1,
  const float* __restrict__ m1w, float* __restrict__ h1)
{
  const int hw=blockIdx.x*256+threadIdx.x;
  const int b=blockIdx.y;
  const int oh=blockIdx.z;           // output half: oh*32 .. +32

  __shared__ float w_sh[ENC_][32];   // [c][o]  12 KB
  __shared__ float a_sh[ENC_], c_sh[ENC_];
  for (int idx=threadIdx.x; idx<ENC_*32; idx+=256){
    int c=idx>>5, o=idx&31;
    w_sh[c][o]=m1w[(oh*32+o)*ENC_+c];
  }
  if (threadIdx.x<ENC_){
    a_sh[threadIdx.x]=cA1[b*ENC_+threadIdx.x];
    c_sh[threadIdx.x]=cB1[b*ENC_+threadIdx.x];
  }
  __syncthreads();

  float acc[32];
#pragma unroll
  for (int o=0;o<32;o++) acc[o]=0.f;

  for (int c0=0;c0<ENC_;c0+=8){
    float g8[8];
#pragma unroll
    for (int j=0;j<8;j++){
      float v=enc[((size_t)b*ENC_+c0+j)*HW_+hw];
      v=fmaf(v,a_sh[c0+j],c_sh[c0+j]);
      g8[j]=gelu_f(v);
    }
#pragma unroll
    for (int j=0;j<8;j++){
#pragma unroll
      for (int o4=0;o4<32;o4+=4){
        float4 w=*(const float4*)&w_sh[c0+j][o4];
        acc[o4+0]=fmaf(w.x,g8[j],acc[o4+0]);
        acc[o4+1]=fmaf(w.y,g8[j],acc[o4+1]);
        acc[o4+2]=fmaf(w.z,g8[j],acc[o4+2]);
        acc[o4+3]=fmaf(w.w,g8[j],acc[o4+3]);
      }
    }
  }
#pragma unroll
  for (int o=0;o<32;o++) h1[((size_t)(b*HID_+oh*32+o))*HW_+hw]=acc[o];
}

// ---------------- kernel E: gelu(GN2) -> mix2 -> softmax -> fused; 16 out-ch per block-z
__global__ __launch_bounds__(256, 4) void kFinal(
  const float* __restrict__ Tf, const float* __restrict__ adW, const float* __restrict__ adB,
  const float* __restrict__ h1, const float* __restrict__ heur,
  const float* __restrict__ cA2, const float* __restrict__ cB2,
  const float* __restrict__ m2w, const float* __restrict__ m2b,
  float* __restrict__ out)
{
  const int hw = blockIdx.x*256+threadIdx.x;
  const int b  = blockIdx.y;
  const int ch = blockIdx.z;                // out channels ch*16 .. +16

  __shared__ float w_sh[S_][16][C_];        // [s][k][i] 16 KB
  __shared__ float m2_sh[HID_][S_];         // [c][s]    1 KB
  __shared__ float a_sh[HID_], c_sh[HID_], bias_sh[S_][16];
  __shared__ float m2b_sh[S_];

  for (int idx=threadIdx.x; idx<S_*16*C_; idx+=256){
    int i=idx&63, k=(idx>>6)&15, s=idx>>10;
    w_sh[s][k][i]=adW[((s*C_)+(ch*16+k))*C_+i];
  }
  for (int idx=threadIdx.x; idx<HID_*S_; idx+=256){
    int s=idx&3, c=idx>>2;
    m2_sh[c][s]=m2w[s*HID_+c];
  }
  if (threadIdx.x<HID_){
    a_sh[threadIdx.x]=cA2[b*HID_+threadIdx.x];
    c_sh[threadIdx.x]=cB2[b*HID_+threadIdx.x];
  }
  if (threadIdx.x<S_*16){
    int s=threadIdx.x>>4, k=threadIdx.x&15;
    bias_sh[s][k]=adB[s*C_+ch*16+k];
  }
  if (threadIdx.x<S_) m2b_sh[threadIdx.x]=m2b[threadIdx.x];
  __syncthreads();

  // logits by streaming h1 channels (no g[] array)
  float la[S_];
#pragma unroll
  for (int s=0;s<S_;s++) la[s]=m2b_sh[s];
  for (int c0=0;c0<HID_;c0+=8){
#pragma unroll
    for (int j=0;j<8;j++){
      float v=h1[((size_t)b*HID_+c0+j)*HW_+hw];
      v=fmaf(v,a_sh[c0+j],c_sh[c0+j]);
      float g=gelu_f(v);
      float4 w=*(const float4*)&m2_sh[c0+j][0];
      la[0]=fmaf(w.x,g,la[0]); la[1]=fmaf(w.y,g,la[1]);
      la[2]=fmaf(w.z,g,la[2]); la[3]=fmaf(w.w,g,la[3]);
    }
  }
  float gate[S_];
  {
    float mx=-1e30f;
#pragma unroll
    for (int s=0;s<S_;s++){
      float hv=heur[((size_t)(b*S_+s))*HW_+hw];
      la[s]=(0.5f*hv+0.5f*la[s])*(1.0f/0.7f);
      mx=fmaxf(mx,la[s]);
    }
    float den=0.f;
#pragma unroll
    for (int s=0;s<S_;s++){ gate[s]=expf(la[s]-mx); den+=gate[s]; }
    float dinv=1.0f/den;
#pragma unroll
    for (int s=0;s<S_;s++) gate[s]*=dinv;
  }

  float oacc[16];
#pragma unroll
  for (int k=0;k<16;k++) oacc[k]=0.f;

  for (int s=0;s<S_;s++){
    const float* tb = Tf + ((size_t)(b*S_+s)*C_)*HW_ + hw;
    float ta[16];
#pragma unroll
    for (int k=0;k<16;k++) ta[k]=bias_sh[s][k];
    for (int i0=0;i0<C_;i0+=8){
      float ti[8];
#pragma unroll
      for (int ii=0;ii<8;ii++) ti[ii]=tb[(size_t)(i0+ii)*HW_];
#pragma unroll
      for (int k=0;k<16;k++){
        float4 w0=*(const float4*)&w_sh[s][k][i0];
        float4 w1=*(const float4*)&w_sh[s][k][i0+4];
        ta[k]=fmaf(w0.x,ti[0],ta[k]); ta[k]=fmaf(w0.y,ti[1],ta[k]);
        ta[k]=fmaf(w0.z,ti[2],ta[k]); ta[k]=fmaf(w0.w,ti[3],ta[k]);
        ta[k]=fmaf(w1.x,ti[4],ta[k]); ta[k]=fmaf(w1.y,ti[5],ta[k]);
        ta[k]=fmaf(w1.z,ti[6],ta[k]); ta[k]=fmaf(w1.w,ti[7],ta[k]);
      }
    }
    float gt=gate[s];
#pragma unroll
    for (int k=0;k<16;k++) oacc[k]=fmaf(gt,ta[k],oacc[k]);
  }
#pragma unroll
  for (int k=0;k<16;k++) out[((size_t)(b*C_+ch*16+k))*HW_+hw]=oacc[k];
}

extern "C" void kernel_launch(void* const* d_in, const int* in_sizes, int n_in,
                              void* d_out, int out_size, void* d_ws, size_t ws_size,
                              hipStream_t stream) {
  (void)in_sizes; (void)n_in; (void)out_size; (void)ws_size;
  const float* Sf    = (const float*)d_in[0];
  const float* Tf    = (const float*)d_in[1];
  const float* adW   = (const float*)d_in[2];
  const float* adB   = (const float*)d_in[3];
  const float* mu    = (const float*)d_in[4];
  const float* sg    = (const float*)d_in[5];
  const float* eprox = (const float*)d_in[6];
  const float* encw  = (const float*)d_in[7];
  const float* gn1g  = (const float*)d_in[8];
  const float* gn1b  = (const float*)d_in[9];
  const float* m1w   = (const float*)d_in[10];
  const float* gn2g  = (const float*)d_in[11];
  const float* gn2b  = (const float*)d_in[12];
  const float* m2w   = (const float*)d_in[13];
  const float* m2b   = (const float*)d_in[14];
  float* out = (float*)d_out;

  float* ws = (float*)d_ws;
  size_t off = 0;
  float* enc  = ws+off; off += (size_t)B_*ENC_*HW_;
  float* h1   = ws+off; off += (size_t)B_*HID_*HW_;
  float* heur = ws+off; off += (size_t)B_*S_*HW_;
  float* E1   = ws+off; off += S_*CO_*C_;
  float* E2   = ws+off; off += S_*CO_*C_;
  float* c0   = ws+off; off += S_*CO_;
  float* ps1  = ws+off; off += B_*32*NSEG;
  float* pq1  = ws+off; off += B_*32*NSEG;
  float* ps2  = ws+off; off += B_*32*NSEG;
  float* pq2  = ws+off; off += B_*32*NSEG;
  float* cA1  = ws+off; off += B_*ENC_;
  float* cB1  = ws+off; off += B_*ENC_;
  float* cA2  = ws+off; off += B_*HID_;
  float* cB2  = ws+off; off += B_*HID_;

  kPrep<<<dim3(24), 256, 0, stream>>>(encw, E1, E2, c0);
  kAdapterEnc<<<dim3(HW_/256, B_, S_), 256, 0, stream>>>(Sf, Tf, adW, adB, mu, sg, eprox,
                                                         E1, E2, c0, enc, heur);
  kStatsPart<<<dim3(32, B_, NSEG), 256, 0, stream>>>(enc, 3, ENC_, ps1, pq1);
  kFinalize<<<1, 64, 0, stream>>>(ps1, pq1, gn1g, gn1b, 3, ENC_, cA1, cB1);
  kMix1<<<dim3(HW_/256, B_, 2), 256, 0, stream>>>(enc, cA1, cB1, m1w, h1);
  kStatsPart<<<dim3(32, B_, NSEG), 256, 0, stream>>>(h1, 2, HID_, ps2, pq2);
  kFinalize<<<1, 64, 0, stream>>>(ps2, pq2, gn2g, gn2b, 2, HID_, cA2, cB2);
  kFinal<<<dim3(HW_/256, B_, 4), 256, 0, stream>>>(Tf, adW, adB, h1, heur,
                                                   cA2, cB2, m2w, m2b, out);
}

// Round 7
// 733.721 us; speedup vs baseline: 1.4965x; 1.4565x over previous
//
#include <hip/hip_runtime.h>
#include <math.h>

#define B_   2
#define S_   4
#define C_   64
#define HW_  65536
#define CI_  194
#define CO_  24
#define ENC_ 96
#define HID_ 64
#define NSEG 8

__device__ __forceinline__ float gelu_f(float x){
  return 0.5f*x*(1.0f+erff(x*0.70710678118654752f));
}

// ---------------- prep: E1 = W_Sz + W_delta, E2 = W_Tz - W_delta, c0 = pos constants
__global__ void kPrep(const float* __restrict__ encw, float* __restrict__ E1,
                      float* __restrict__ E2, float* __restrict__ c0){
  int t = blockIdx.x*blockDim.x + threadIdx.x;
  int tot = S_*CO_*C_;
  for (int idx=t; idx<tot; idx += gridDim.x*blockDim.x){
    int c  = idx & (C_-1);
    int so = idx >> 6;            // s*CO + o
    const float* row = encw + so*CI_;
    E1[idx] = row[c]      + row[2*C_+c];
    E2[idx] = row[C_+c]   - row[2*C_+c];
  }
  if (t < S_*CO_){
    int s = t / CO_;
    float idxv = (float)s / 3.0f;
    float ang  = 6.283185307179586f * idxv;
    const float* row = encw + t*CI_;
    c0[t] = row[3*C_]*sinf(ang) + row[3*C_+1]*cosf(ang);
  }
}

// ---------------- kernel A: adapter matvecs, proxy/heur, enc, T_adapt out — one (b,s) per block-z
__global__ __launch_bounds__(256, 4) void kAdapterEnc(
    const float* __restrict__ Sf, const float* __restrict__ Tf,
    const float* __restrict__ adW, const float* __restrict__ adB,
    const float* __restrict__ mu, const float* __restrict__ sg,
    const float* __restrict__ eproxy,
    const float* __restrict__ E1, const float* __restrict__ E2,
    const float* __restrict__ c0,
    float* __restrict__ enc, float* __restrict__ heur, float* __restrict__ Ta)
{
  const int hw = blockIdx.x*256 + threadIdx.x;
  const int b  = blockIdx.y;
  const int s  = blockIdx.z;

  __shared__ float w_sh[C_][C_];       // [oc][i]  16 KB
  __shared__ float e_sh[C_][2*CO_];    // [oc][e]=E1, [oc][CO_+e]=E2   12 KB
  __shared__ float bias_sh[C_], mu_sh[C_], inv_sh[C_], c0_sh[CO_];

  for (int idx=threadIdx.x; idx<C_*C_; idx+=256){
    int oc=idx>>6, i=idx&63;
    w_sh[oc][i] = adW[(s*C_+oc)*C_+i];
  }
  for (int idx=threadIdx.x; idx<C_*CO_; idx+=256){
    int oc=idx/CO_, e=idx-oc*CO_;
    e_sh[oc][e]     = E1[(s*CO_+e)*C_+oc];
    e_sh[oc][CO_+e] = E2[(s*CO_+e)*C_+oc];
  }
  if (threadIdx.x<C_){
    bias_sh[threadIdx.x]=adB[s*C_+threadIdx.x];
    mu_sh[threadIdx.x]  =mu [s*C_+threadIdx.x];
    inv_sh[threadIdx.x] =1.0f/fmaxf(sg[s*C_+threadIdx.x],1e-3f);
  }
  if (threadIdx.x<CO_) c0_sh[threadIdx.x]=c0[s*CO_+threadIdx.x];
  __syncthreads();

  const float* tbase = Tf + ((size_t)(b*S_+s)*C_)*HW_ + hw;
  const float* sbase = Sf + ((size_t)b*C_)*HW_ + hw;
  float* tabase      = Ta + ((size_t)(b*S_+s)*C_)*HW_ + hw;

  float eacc[CO_];
#pragma unroll
  for (int e=0;e<CO_;e++) eacc[e]=c0_sh[e];
  float pacc=0.f;

  for (int oc0=0; oc0<C_; oc0+=16){
    float ta[16], sr[16];
#pragma unroll
    for (int k=0;k<16;k++){ ta[k]=bias_sh[oc0+k]; sr[k]=ta[k]; }

    for (int i0=0;i0<C_;i0+=8){
      float ti[8], si[8];
#pragma unroll
      for (int ii=0;ii<8;ii++){
        ti[ii]=tbase[(size_t)(i0+ii)*HW_];
        si[ii]=sbase[(size_t)(i0+ii)*HW_];
      }
#pragma unroll
      for (int k=0;k<16;k++){
        float4 w0=*(const float4*)&w_sh[oc0+k][i0];
        float4 w1=*(const float4*)&w_sh[oc0+k][i0+4];
        ta[k]=fmaf(w0.x,ti[0],ta[k]); sr[k]=fmaf(w0.x,si[0],sr[k]);
        ta[k]=fmaf(w0.y,ti[1],ta[k]); sr[k]=fmaf(w0.y,si[1],sr[k]);
        ta[k]=fmaf(w0.z,ti[2],ta[k]); sr[k]=fmaf(w0.z,si[2],sr[k]);
        ta[k]=fmaf(w0.w,ti[3],ta[k]); sr[k]=fmaf(w0.w,si[3],sr[k]);
        ta[k]=fmaf(w1.x,ti[4],ta[k]); sr[k]=fmaf(w1.x,si[4],sr[k]);
        ta[k]=fmaf(w1.y,ti[5],ta[k]); sr[k]=fmaf(w1.y,si[5],sr[k]);
        ta[k]=fmaf(w1.z,ti[6],ta[k]); sr[k]=fmaf(w1.z,si[6],sr[k]);
        ta[k]=fmaf(w1.w,ti[7],ta[k]); sr[k]=fmaf(w1.w,si[7],sr[k]);
      }
    }
    // write T_adapt, normalize + proxy + enc accumulate for this oc chunk
#pragma unroll
    for (int k=0;k<16;k++){
      int oc=oc0+k;
      tabase[(size_t)oc*HW_] = ta[k];
      float m=mu_sh[oc], inv=inv_sh[oc];
      float tz=(ta[k]-m)*inv;
      float sz=(sr[k]-m)*inv;
      float d=sz-tz; pacc=fmaf(d,d,pacc);
#pragma unroll
      for (int e0=0;e0<CO_;e0+=4){
        float4 E1v=*(const float4*)&e_sh[oc][e0];
        float4 E2v=*(const float4*)&e_sh[oc][CO_+e0];
        eacc[e0+0]=fmaf(E1v.x,sz,fmaf(E2v.x,tz,eacc[e0+0]));
        eacc[e0+1]=fmaf(E1v.y,sz,fmaf(E2v.y,tz,eacc[e0+1]));
        eacc[e0+2]=fmaf(E1v.z,sz,fmaf(E2v.z,tz,eacc[e0+2]));
        eacc[e0+3]=fmaf(E1v.w,sz,fmaf(E2v.w,tz,eacc[e0+3]));
      }
    }
  }

  float proxy = pacc*(1.0f/(float)C_);
  float adv   = proxy - eproxy[s];
  float band  = (proxy>=0.05f && proxy<=0.2f)?1.0f:0.0f;
  heur[((size_t)(b*S_+s))*HW_+hw] = adv + 0.5f*band;
#pragma unroll
  for (int e=0;e<CO_;e++) enc[((size_t)((b*S_+s)*CO_+e))*HW_+hw] = eacc[e];
}

// ---------------- segmented group-norm stats
__global__ __launch_bounds__(256) void kStatsPart(const float* __restrict__ x, int npg, int nct,
  float* __restrict__ psum, float* __restrict__ psq)
{
  const int g=blockIdx.x, b=blockIdx.y, seg=blockIdx.z;
  const int F4_PER_SEG = HW_/4/NSEG;   // 2048
  float sum=0.f, sq=0.f;
  for (int j=0;j<npg;j++){
    const float4* row=(const float4*)(x + (size_t)(b*nct+g*npg+j)*HW_) + seg*F4_PER_SEG;
    for (int i=threadIdx.x;i<F4_PER_SEG;i+=256){
      float4 v=row[i];
      sum += (v.x+v.y)+(v.z+v.w);
      sq = fmaf(v.x,v.x,sq); sq=fmaf(v.y,v.y,sq); sq=fmaf(v.z,v.z,sq); sq=fmaf(v.w,v.w,sq);
    }
  }
#pragma unroll
  for (int off=32;off>=1;off>>=1){ sum+=__shfl_xor(sum,off); sq+=__shfl_xor(sq,off); }
  __shared__ float ss[4], qq[4];
  int wid=threadIdx.x>>6, lane=threadIdx.x&63;
  if(lane==0){ ss[wid]=sum; qq[wid]=sq; }
  __syncthreads();
  if(threadIdx.x==0){
    psum[(b*32+g)*NSEG+seg]=ss[0]+ss[1]+ss[2]+ss[3];
    psq [(b*32+g)*NSEG+seg]=qq[0]+qq[1]+qq[2]+qq[3];
  }
}

// ---------------- finalize GN coefficients
__global__ void kFinalize(const float* __restrict__ psum, const float* __restrict__ psq,
  const float* __restrict__ gamma, const float* __restrict__ beta,
  int npg, int nct, float* __restrict__ cA, float* __restrict__ cB)
{
  int t=threadIdx.x;
  if (t < B_*32){
    int b=t>>5, g=t&31;
    float Ssum=0.f,Q=0.f;
    for(int k=0;k<NSEG;k++){ Ssum+=psum[t*NSEG+k]; Q+=psq[t*NSEG+k]; }
    float n=(float)npg*(float)HW_;
    float mean=Ssum/n;
    float var=Q/n-mean*mean;
    float inv=1.0f/sqrtf(var+1e-5f);
    for(int j=0;j<npg;j++){
      int c=g*npg+j;
      float a=gamma[c]*inv;
      cA[b*nct+c]=a;
      cB[b*nct+c]=beta[c]-mean*a;
    }
  }
}

// ---------------- kernel C: gelu(GN1(enc)) -> mix1 (half of outputs per block-z)
__global__ __launch_bounds__(256, 4) void kMix1(
  const float* __restrict__ enc, const float* __restrict__ cA1, const float* __restrict__ cB1,
  const float* __restrict__ m1w, float* __restrict__ h1)
{
  const int hw=blockIdx.x*256+threadIdx.x;
  const int b=blockIdx.y;
  const int oh=blockIdx.z;           // output half: oh*32 .. +32

  __shared__ float w_sh[ENC_][32];   // [c][o]  12 KB
  __shared__ float a_sh[ENC_], c_sh[ENC_];
  for (int idx=threadIdx.x; idx<ENC_*32; idx+=256){
    int c=idx>>5, o=idx&31;
    w_sh[c][o]=m1w[(oh*32+o)*ENC_+c];
  }
  if (threadIdx.x<ENC_){
    a_sh[threadIdx.x]=cA1[b*ENC_+threadIdx.x];
    c_sh[threadIdx.x]=cB1[b*ENC_+threadIdx.x];
  }
  __syncthreads();

  float acc[32];
#pragma unroll
  for (int o=0;o<32;o++) acc[o]=0.f;

  for (int c0=0;c0<ENC_;c0+=8){
    float g8[8];
#pragma unroll
    for (int j=0;j<8;j++){
      float v=enc[((size_t)b*ENC_+c0+j)*HW_+hw];
      v=fmaf(v,a_sh[c0+j],c_sh[c0+j]);
      g8[j]=gelu_f(v);
    }
#pragma unroll
    for (int j=0;j<8;j++){
#pragma unroll
      for (int o4=0;o4<32;o4+=4){
        float4 w=*(const float4*)&w_sh[c0+j][o4];
        acc[o4+0]=fmaf(w.x,g8[j],acc[o4+0]);
        acc[o4+1]=fmaf(w.y,g8[j],acc[o4+1]);
        acc[o4+2]=fmaf(w.z,g8[j],acc[o4+2]);
        acc[o4+3]=fmaf(w.w,g8[j],acc[o4+3]);
      }
    }
  }
#pragma unroll
  for (int o=0;o<32;o++) h1[((size_t)(b*HID_+oh*32+o))*HW_+hw]=acc[o];
}

// ---------------- kernel E: gelu(GN2) -> mix2 -> softmax -> streaming fuse of stored T_adapt
__global__ __launch_bounds__(256, 4) void kFinal(
  const float* __restrict__ Ta, const float* __restrict__ h1,
  const float* __restrict__ heur,
  const float* __restrict__ cA2, const float* __restrict__ cB2,
  const float* __restrict__ m2w, const float* __restrict__ m2b,
  float* __restrict__ out)
{
  const int hw = blockIdx.x*256+threadIdx.x;
  const int b  = blockIdx.y;
  const int ch = blockIdx.z;                // out channels ch*32 .. +32

  __shared__ float m2_sh[HID_][S_];         // [c][s]  1 KB
  __shared__ float a_sh[HID_], c_sh[HID_];
  __shared__ float m2b_sh[S_];

  for (int idx=threadIdx.x; idx<HID_*S_; idx+=256){
    int s=idx&3, c=idx>>2;
    m2_sh[c][s]=m2w[s*HID_+c];
  }
  if (threadIdx.x<HID_){
    a_sh[threadIdx.x]=cA2[b*HID_+threadIdx.x];
    c_sh[threadIdx.x]=cB2[b*HID_+threadIdx.x];
  }
  if (threadIdx.x<S_) m2b_sh[threadIdx.x]=m2b[threadIdx.x];
  __syncthreads();

  // logits by streaming h1 channels
  float la[S_];
#pragma unroll
  for (int s=0;s<S_;s++) la[s]=m2b_sh[s];
  for (int c0=0;c0<HID_;c0+=8){
#pragma unroll
    for (int j=0;j<8;j++){
      float v=h1[((size_t)b*HID_+c0+j)*HW_+hw];
      v=fmaf(v,a_sh[c0+j],c_sh[c0+j]);
      float g=gelu_f(v);
      float4 w=*(const float4*)&m2_sh[c0+j][0];
      la[0]=fmaf(w.x,g,la[0]); la[1]=fmaf(w.y,g,la[1]);
      la[2]=fmaf(w.z,g,la[2]); la[3]=fmaf(w.w,g,la[3]);
    }
  }
  float g0,g1,g2,g3;
  {
    float mx=-1e30f;
#pragma unroll
    for (int s=0;s<S_;s++){
      float hv=heur[((size_t)(b*S_+s))*HW_+hw];
      la[s]=(0.5f*hv+0.5f*la[s])*(1.0f/0.7f);
      mx=fmaxf(mx,la[s]);
    }
    float e0=expf(la[0]-mx), e1=expf(la[1]-mx), e2=expf(la[2]-mx), e3=expf(la[3]-mx);
    float dinv=1.0f/(e0+e1+e2+e3);
    g0=e0*dinv; g1=e1*dinv; g2=e2*dinv; g3=e3*dinv;
  }

  // streaming fuse: out[c] = sum_s gate_s * Ta[b][s][c][hw]
  const float* ta0 = Ta + ((size_t)(b*S_+0)*C_ + ch*32)*HW_ + hw;
  const float* ta1 = ta0 + (size_t)C_*HW_;
  const float* ta2 = ta1 + (size_t)C_*HW_;
  const float* ta3 = ta2 + (size_t)C_*HW_;
  float* ob = out + ((size_t)(b*C_) + ch*32)*HW_ + hw;
#pragma unroll 8
  for (int k=0;k<32;k++){
    size_t o=(size_t)k*HW_;
    float v = g0*ta0[o];
    v = fmaf(g1, ta1[o], v);
    v = fmaf(g2, ta2[o], v);
    v = fmaf(g3, ta3[o], v);
    ob[o]=v;
  }
}

extern "C" void kernel_launch(void* const* d_in, const int* in_sizes, int n_in,
                              void* d_out, int out_size, void* d_ws, size_t ws_size,
                              hipStream_t stream) {
  (void)in_sizes; (void)n_in; (void)out_size; (void)ws_size;
  const float* Sf    = (const float*)d_in[0];
  const float* Tf    = (const float*)d_in[1];
  const float* adW   = (const float*)d_in[2];
  const float* adB   = (const float*)d_in[3];
  const float* mu    = (const float*)d_in[4];
  const float* sg    = (const float*)d_in[5];
  const float* eprox = (const float*)d_in[6];
  const float* encw  = (const float*)d_in[7];
  const float* gn1g  = (const float*)d_in[8];
  const float* gn1b  = (const float*)d_in[9];
  const float* m1w   = (const float*)d_in[10];
  const float* gn2g  = (const float*)d_in[11];
  const float* gn2b  = (const float*)d_in[12];
  const float* m2w   = (const float*)d_in[13];
  const float* m2b   = (const float*)d_in[14];
  float* out = (float*)d_out;

  float* ws = (float*)d_ws;
  size_t off = 0;
  float* Ta   = ws+off; off += (size_t)B_*S_*C_*HW_;  // 33,554,432 floats (134 MB)
  float* enc  = ws+off; off += (size_t)B_*ENC_*HW_;   // 12,582,912
  float* h1   = ws+off; off += (size_t)B_*HID_*HW_;   //  8,388,608
  float* heur = ws+off; off += (size_t)B_*S_*HW_;     //    524,288
  float* E1   = ws+off; off += S_*CO_*C_;
  float* E2   = ws+off; off += S_*CO_*C_;
  float* c0   = ws+off; off += S_*CO_;
  float* ps1  = ws+off; off += B_*32*NSEG;
  float* pq1  = ws+off; off += B_*32*NSEG;
  float* ps2  = ws+off; off += B_*32*NSEG;
  float* pq2  = ws+off; off += B_*32*NSEG;
  float* cA1  = ws+off; off += B_*ENC_;
  float* cB1  = ws+off; off += B_*ENC_;
  float* cA2  = ws+off; off += B_*HID_;
  float* cB2  = ws+off; off += B_*HID_;

  kPrep<<<dim3(24), 256, 0, stream>>>(encw, E1, E2, c0);
  kAdapterEnc<<<dim3(HW_/256, B_, S_), 256, 0, stream>>>(Sf, Tf, adW, adB, mu, sg, eprox,
                                                         E1, E2, c0, enc, heur, Ta);
  kStatsPart<<<dim3(32, B_, NSEG), 256, 0, stream>>>(enc, 3, ENC_, ps1, pq1);
  kFinalize<<<1, 64, 0, stream>>>(ps1, pq1, gn1g, gn1b, 3, ENC_, cA1, cB1);
  kMix1<<<dim3(HW_/256, B_, 2), 256, 0, stream>>>(enc, cA1, cB1, m1w, h1);
  kStatsPart<<<dim3(32, B_, NSEG), 256, 0, stream>>>(h1, 2, HID_, ps2, pq2);
  kFinalize<<<1, 64, 0, stream>>>(ps2, pq2, gn2g, gn2b, 2, HID_, cA2, cB2);
  kFinal<<<dim3(HW_/256, B_, 2), 256, 0, stream>>>(Ta, h1, heur,
                                                   cA2, cB2, m2w, m2b, out);
}

// Round 11
// 628.333 us; speedup vs baseline: 1.7476x; 1.1677x over previous
//
#include <hip/hip_runtime.h>
#include <math.h>

#define B_   2
#define S_   4
#define C_   64
#define HW_  65536
#define CI_  194
#define CO_  24
#define ENC_ 96
#define HID_ 64

__device__ __forceinline__ float gelu_f(float x){
  return 0.5f*x*(1.0f+erff(x*0.70710678118654752f));
}

// ---------------- prep: E1t/E2t transposed to [s][oc][e], c0, zero stats accumulators
__global__ void kPrep(const float* __restrict__ encw, float* __restrict__ E1t,
                      float* __restrict__ E2t, float* __restrict__ c0,
                      float* __restrict__ gs1, float* __restrict__ gq1,
                      float* __restrict__ gs2, float* __restrict__ gq2){
  int t = blockIdx.x*blockDim.x + threadIdx.x;
  int tot = S_*C_*CO_;
  for (int idx=t; idx<tot; idx += gridDim.x*blockDim.x){
    int e   = idx % CO_;
    int soc = idx / CO_;
    int oc  = soc & (C_-1);
    int s   = soc >> 6;
    const float* row = encw + (s*CO_+e)*CI_;
    E1t[idx] = row[oc]      + row[2*C_+oc];
    E2t[idx] = row[C_+oc]   - row[2*C_+oc];
  }
  if (t < S_*CO_){
    int s = t / CO_;
    float idxv = (float)s / 3.0f;
    float ang  = 6.283185307179586f * idxv;
    const float* row = encw + t*CI_;
    c0[t] = row[3*C_]*sinf(ang) + row[3*C_+1]*cosf(ang);
  }
  if (blockIdx.x==0 && threadIdx.x < B_*32){
    gs1[threadIdx.x]=0.f; gq1[threadIdx.x]=0.f;
    gs2[threadIdx.x]=0.f; gq2[threadIdx.x]=0.f;
  }
}

// ---------------- kernel A: adapter matvecs (scalar weights), proxy/heur, enc, Ta, GN1 stats
__global__ __launch_bounds__(256, 5) void kAdapterEnc(
    const float* __restrict__ Sf, const float* __restrict__ Tf,
    const float* __restrict__ adW, const float* __restrict__ adB,
    const float* __restrict__ mu, const float* __restrict__ sg,
    const float* __restrict__ eproxy,
    const float* __restrict__ E1t, const float* __restrict__ E2t,
    const float* __restrict__ c0,
    float* __restrict__ enc, float* __restrict__ heur, float* __restrict__ Ta,
    float* __restrict__ gs1, float* __restrict__ gq1)
{
  const int hw = blockIdx.x*256 + threadIdx.x;
  const int b  = blockIdx.y;
  const int s  = blockIdx.z;

  const float* tbase = Tf + ((size_t)(b*S_+s)*C_)*HW_ + hw;
  const float* sbase = Sf + ((size_t)b*C_)*HW_ + hw;
  float* tabase      = Ta + ((size_t)(b*S_+s)*C_)*HW_ + hw;

  float eacc[CO_];
#pragma unroll
  for (int e=0;e<CO_;e++) eacc[e]=c0[s*CO_+e];
  float pacc=0.f;

  for (int oc0=0; oc0<C_; oc0+=16){
    float ta[16], sr[16];
#pragma unroll
    for (int k=0;k<16;k++){ float bb=adB[s*C_+oc0+k]; ta[k]=bb; sr[k]=bb; }

    for (int i0=0;i0<C_;i0+=8){
      float ti[8], si[8];
#pragma unroll
      for (int ii=0;ii<8;ii++){
        ti[ii]=tbase[(size_t)(i0+ii)*HW_];
        si[ii]=sbase[(size_t)(i0+ii)*HW_];
      }
#pragma unroll
      for (int k=0;k<16;k++){
        const float* wr = adW + (size_t)(s*C_+oc0+k)*C_ + i0;   // wave-uniform -> s_load
#pragma unroll
        for (int ii=0;ii<8;ii++){
          float w = wr[ii];
          ta[k]=fmaf(w,ti[ii],ta[k]);
          sr[k]=fmaf(w,si[ii],sr[k]);
        }
      }
    }
    // write T_adapt, normalize + proxy + enc accumulate for this oc chunk
#pragma unroll
    for (int k=0;k<16;k++){
      int oc=oc0+k;
      tabase[(size_t)oc*HW_] = ta[k];
      float m   = mu[s*C_+oc];
      float sig = fmaxf(sg[s*C_+oc],1e-3f);
      float inv = 1.0f/sig;
      float tz=(ta[k]-m)*inv;
      float sz=(sr[k]-m)*inv;
      float d=sz-tz; pacc=fmaf(d,d,pacc);
      const float* e1 = E1t + (size_t)(s*C_+oc)*CO_;            // wave-uniform -> s_load
      const float* e2 = E2t + (size_t)(s*C_+oc)*CO_;
#pragma unroll
      for (int e=0;e<CO_;e++)
        eacc[e]=fmaf(e1[e],sz,fmaf(e2[e],tz,eacc[e]));
    }
  }

  float proxy = pacc*(1.0f/(float)C_);
  float adv   = proxy - eproxy[s];
  float band  = (proxy>=0.05f && proxy<=0.2f)?1.0f:0.0f;
  heur[((size_t)(b*S_+s))*HW_+hw] = adv + 0.5f*band;
#pragma unroll
  for (int e=0;e<CO_;e++) enc[((size_t)((b*S_+s)*CO_+e))*HW_+hw] = eacc[e];

  // fused GN1 partial stats: this block covers groups 8s..8s+7 (3 channels each)
  __shared__ float red[2][4][8];
  int lane=threadIdx.x&63, wid=threadIdx.x>>6;
#pragma unroll
  for (int j=0;j<8;j++){
    float sm = eacc[3*j]+eacc[3*j+1]+eacc[3*j+2];
    float sq = eacc[3*j]*eacc[3*j]+eacc[3*j+1]*eacc[3*j+1]+eacc[3*j+2]*eacc[3*j+2];
#pragma unroll
    for (int off=32;off>=1;off>>=1){ sm+=__shfl_xor(sm,off); sq+=__shfl_xor(sq,off); }
    if (lane==0){ red[0][wid][j]=sm; red[1][wid][j]=sq; }
  }
  __syncthreads();
  if (threadIdx.x<16){
    int j=threadIdx.x&7, which=threadIdx.x>>3;
    float v = red[which][0][j]+red[which][1][j]+red[which][2][j]+red[which][3][j];
    float* dst = which ? gq1 : gs1;
    atomicAdd(&dst[b*32 + 8*s + j], v);
  }
}

// ---------------- finalize GN coefficients from atomic sums
__global__ void kFinalize(const float* __restrict__ gsum, const float* __restrict__ gsq,
  const float* __restrict__ gamma, const float* __restrict__ beta,
  int npg, int nct, float* __restrict__ cA, float* __restrict__ cB)
{
  int t=threadIdx.x;
  if (t < B_*32){
    int b=t>>5, g=t&31;
    float Ssum=gsum[t], Q=gsq[t];
    float n=(float)npg*(float)HW_;
    float mean=Ssum/n;
    float var=Q/n-mean*mean;
    float inv=1.0f/sqrtf(var+1e-5f);
    for(int j=0;j<npg;j++){
      int c=g*npg+j;
      float a=gamma[c]*inv;
      cA[b*nct+c]=a;
      cB[b*nct+c]=beta[c]-mean*a;
    }
  }
}

// ---------------- kernel C: gelu(GN1(enc)) -> mix1 (scalar weights) + GN2 stats
__global__ __launch_bounds__(256, 6) void kMix1(
  const float* __restrict__ enc, const float* __restrict__ cA1, const float* __restrict__ cB1,
  const float* __restrict__ m1w, float* __restrict__ h1,
  float* __restrict__ gs2, float* __restrict__ gq2)
{
  const int hw=blockIdx.x*256+threadIdx.x;
  const int b=blockIdx.y;
  const int oh=blockIdx.z;           // output half: oh*32 .. +32

  float acc[32];
#pragma unroll
  for (int o=0;o<32;o++) acc[o]=0.f;

  for (int c0=0;c0<ENC_;c0+=8){
    float g8[8];
#pragma unroll
    for (int j=0;j<8;j++){
      float v=enc[((size_t)b*ENC_+c0+j)*HW_+hw];
      v=fmaf(v,cA1[b*ENC_+c0+j],cB1[b*ENC_+c0+j]);
      g8[j]=gelu_f(v);
    }
#pragma unroll
    for (int o=0;o<32;o++){
      const float* wr = m1w + (size_t)(oh*32+o)*ENC_ + c0;     // wave-uniform -> s_load
      float a=acc[o];
      a=fmaf(wr[0],g8[0],a); a=fmaf(wr[1],g8[1],a);
      a=fmaf(wr[2],g8[2],a); a=fmaf(wr[3],g8[3],a);
      a=fmaf(wr[4],g8[4],a); a=fmaf(wr[5],g8[5],a);
      a=fmaf(wr[6],g8[6],a); a=fmaf(wr[7],g8[7],a);
      acc[o]=a;
    }
  }
#pragma unroll
  for (int o=0;o<32;o++) h1[((size_t)(b*HID_+oh*32+o))*HW_+hw]=acc[o];

  // fused GN2 partial stats: groups oh*16 .. oh*16+15 (2 channels each)
  __shared__ float red[2][4][16];
  int lane=threadIdx.x&63, wid=threadIdx.x>>6;
#pragma unroll
  for (int j=0;j<16;j++){
    float sm = acc[2*j]+acc[2*j+1];
    float sq = acc[2*j]*acc[2*j]+acc[2*j+1]*acc[2*j+1];
#pragma unroll
    for (int off=32;off>=1;off>>=1){ sm+=__shfl_xor(sm,off); sq+=__shfl_xor(sq,off); }
    if (lane==0){ red[0][wid][j]=sm; red[1][wid][j]=sq; }
  }
  __syncthreads();
  if (threadIdx.x<32){
    int j=threadIdx.x&15, which=threadIdx.x>>4;
    float v = red[which][0][j]+red[which][1][j]+red[which][2][j]+red[which][3][j];
    float* dst = which ? gq2 : gs2;
    atomicAdd(&dst[b*32 + oh*16 + j], v);
  }
}

// ---------------- kernel E: gelu(GN2) -> mix2 -> softmax -> streaming fuse of stored T_adapt
__global__ __launch_bounds__(256, 4) void kFinal(
  const float* __restrict__ Ta, const float* __restrict__ h1,
  const float* __restrict__ heur,
  const float* __restrict__ cA2, const float* __restrict__ cB2,
  const float* __restrict__ m2w, const float* __restrict__ m2b,
  float* __restrict__ out)
{
  const int hw = blockIdx.x*256+threadIdx.x;
  const int b  = blockIdx.y;
  const int ch = blockIdx.z;                // out channels ch*32 .. +32

  // logits by streaming h1 channels (all params scalar-loaded)
  float la[S_];
#pragma unroll
  for (int s=0;s<S_;s++) la[s]=m2b[s];
  for (int c0=0;c0<HID_;c0+=8){
#pragma unroll
    for (int j=0;j<8;j++){
      int c=c0+j;
      float v=h1[((size_t)b*HID_+c)*HW_+hw];
      v=fmaf(v,cA2[b*HID_+c],cB2[b*HID_+c]);
      float g=gelu_f(v);
      la[0]=fmaf(m2w[0*HID_+c],g,la[0]);
      la[1]=fmaf(m2w[1*HID_+c],g,la[1]);
      la[2]=fmaf(m2w[2*HID_+c],g,la[2]);
      la[3]=fmaf(m2w[3*HID_+c],g,la[3]);
    }
  }
  float g0,g1,g2,g3;
  {
    float mx=-1e30f;
#pragma unroll
    for (int s=0;s<S_;s++){
      float hv=heur[((size_t)(b*S_+s))*HW_+hw];
      la[s]=(0.5f*hv+0.5f*la[s])*(1.0f/0.7f);
      mx=fmaxf(mx,la[s]);
    }
    float e0=expf(la[0]-mx), e1=expf(la[1]-mx), e2=expf(la[2]-mx), e3=expf(la[3]-mx);
    float dinv=1.0f/(e0+e1+e2+e3);
    g0=e0*dinv; g1=e1*dinv; g2=e2*dinv; g3=e3*dinv;
  }

  // streaming fuse: out[c] = sum_s gate_s * Ta[b][s][c][hw]
  const float* ta0 = Ta + ((size_t)(b*S_+0)*C_ + ch*32)*HW_ + hw;
  const float* ta1 = ta0 + (size_t)C_*HW_;
  const float* ta2 = ta1 + (size_t)C_*HW_;
  const float* ta3 = ta2 + (size_t)C_*HW_;
  float* ob = out + ((size_t)(b*C_) + ch*32)*HW_ + hw;
#pragma unroll 8
  for (int k=0;k<32;k++){
    size_t o=(size_t)k*HW_;
    float v = g0*ta0[o];
    v = fmaf(g1, ta1[o], v);
    v = fmaf(g2, ta2[o], v);
    v = fmaf(g3, ta3[o], v);
    ob[o]=v;
  }
}

extern "C" void kernel_launch(void* const* d_in, const int* in_sizes, int n_in,
                              void* d_out, int out_size, void* d_ws, size_t ws_size,
                              hipStream_t stream) {
  (void)in_sizes; (void)n_in; (void)out_size; (void)ws_size;
  const float* Sf    = (const float*)d_in[0];
  const float* Tf    = (const float*)d_in[1];
  const float* adW   = (const float*)d_in[2];
  const float* adB   = (const float*)d_in[3];
  const float* mu    = (const float*)d_in[4];
  const float* sg    = (const float*)d_in[5];
  const float* eprox = (const float*)d_in[6];
  const float* encw  = (const float*)d_in[7];
  const float* gn1g  = (const float*)d_in[8];
  const float* gn1b  = (const float*)d_in[9];
  const float* m1w   = (const float*)d_in[10];
  const float* gn2g  = (const float*)d_in[11];
  const float* gn2b  = (const float*)d_in[12];
  const float* m2w   = (const float*)d_in[13];
  const float* m2b   = (const float*)d_in[14];
  float* out = (float*)d_out;

  float* ws = (float*)d_ws;
  size_t off = 0;
  float* Ta   = ws+off; off += (size_t)B_*S_*C_*HW_;  // 134 MB
  float* enc  = ws+off; off += (size_t)B_*ENC_*HW_;   //  50 MB
  float* h1   = ws+off; off += (size_t)B_*HID_*HW_;   //  33.5 MB
  float* heur = ws+off; off += (size_t)B_*S_*HW_;     //   2 MB
  float* E1t  = ws+off; off += S_*C_*CO_;
  float* E2t  = ws+off; off += S_*C_*CO_;
  float* c0   = ws+off; off += S_*CO_;
  float* gs1  = ws+off; off += B_*32;
  float* gq1  = ws+off; off += B_*32;
  float* gs2  = ws+off; off += B_*32;
  float* gq2  = ws+off; off += B_*32;
  float* cA1  = ws+off; off += B_*ENC_;
  float* cB1  = ws+off; off += B_*ENC_;
  float* cA2  = ws+off; off += B_*HID_;
  float* cB2  = ws+off; off += B_*HID_;

  kPrep<<<dim3(24), 256, 0, stream>>>(encw, E1t, E2t, c0, gs1, gq1, gs2, gq2);
  kAdapterEnc<<<dim3(HW_/256, B_, S_), 256, 0, stream>>>(Sf, Tf, adW, adB, mu, sg, eprox,
                                                         E1t, E2t, c0, enc, heur, Ta,
                                                         gs1, gq1);
  kFinalize<<<1, 64, 0, stream>>>(gs1, gq1, gn1g, gn1b, 3, ENC_, cA1, cB1);
  kMix1<<<dim3(HW_/256, B_, 2), 256, 0, stream>>>(enc, cA1, cB1, m1w, h1, gs2, gq2);
  kFinalize<<<1, 64, 0, stream>>>(gs2, gq2, gn2g, gn2b, 2, HID_, cA2, cB2);
  kFinal<<<dim3(HW_/256, B_, 2), 256, 0, stream>>>(Ta, h1, heur,
                                                   cA2, cB2, m2w, m2b, out);
}